// Round 3
// baseline (67816.528 us; speedup 1.0000x reference)
//
#include <hip/hip_runtime.h>
#include <stdint.h>

#define S_LEN 2048

typedef unsigned long long u64;
typedef unsigned int u32;
typedef __attribute__((ext_vector_type(8))) short short8;
typedef __attribute__((ext_vector_type(4))) float f32x4;

// u32 index into Hx/RHx: [buf 2][grp 2][m 16][col 512], word = (tag16<<16)|bf16
#define XIDX(pbuf, grp, m, c) (((((pbuf)*2 + (grp))*16 + (m))*512) + (c))

__device__ __forceinline__ unsigned short f2bf(float f) {
  union { float f; u32 u; } v; v.f = f;
  u32 u = v.u;
  u = (u + 0x7FFFu + ((u >> 16) & 1u)) >> 16;   // round-to-nearest-even
  return (unsigned short)u;
}
__device__ __forceinline__ float bf2f(u32 lo16) {
  union { u32 u; float f; } v; v.u = lo16 << 16; return v.f;
}
__device__ __forceinline__ u32 cvt2bf(float lo, float hi) {
  u32 r; asm("v_cvt_pk_bf16_f32 %0, %1, %2" : "=v"(r) : "v"(lo), "v"(hi)); return r;
}

__device__ __forceinline__ void st_u32(u32* p, u32 v) {
  __hip_atomic_store(p, v, __ATOMIC_RELAXED, __HIP_MEMORY_SCOPE_AGENT);
}
__device__ __forceinline__ u32 ld_u32(const u32* p) {
  return __hip_atomic_load(p, __ATOMIC_RELAXED, __HIP_MEMORY_SCOPE_AGENT);
}
__device__ __forceinline__ u64 ld_u64a(const u64* p) {
  return __hip_atomic_load(p, __ATOMIC_RELAXED, __HIP_MEMORY_SCOPE_AGENT);
}

// Load the 16-chunk tile (64 u64 = 128 tagged words) and report validity.
__device__ __forceinline__ bool poll_tile(const u64* base, u64 pat, u64 (&raw)[64]) {
  u64 acc = 0;
#pragma unroll
  for (int kk = 0; kk < 16; ++kk)
#pragma unroll
    for (int q = 0; q < 4; ++q) {
      u64 v = ld_u64a(base + kk * 16 + q);
      raw[kk * 4 + q] = v;
      acc |= v ^ pat;
    }
  return (acc & 0xFFFF0000FFFF0000ULL) == 0;
}

// Pack 4 tagged u64 (8 words) -> 8 bf16 fragment
__device__ __forceinline__ short8 mk8(const u64* r) {
  union { u32 w[4]; short8 v; } u;
#pragma unroll
  for (int q = 0; q < 4; ++q)
    u.w[q] = (u32)(r[q] & 0xFFFFu) | (u32)((r[q] >> 16) & 0xFFFF0000u);
  return u.v;
}

__device__ __forceinline__ f32x4 gemm18(const unsigned short* Bb, short8 xa0, short8 xa1,
                                        const u64 (&raw)[64]) {
  f32x4 a0 = {0.f, 0.f, 0.f, 0.f}, a1 = {0.f, 0.f, 0.f, 0.f};
  a0 = __builtin_amdgcn_mfma_f32_16x16x32_bf16(xa0, *(const short8*)(Bb + 0 * 512), a0, 0, 0, 0);
  a1 = __builtin_amdgcn_mfma_f32_16x16x32_bf16(xa1, *(const short8*)(Bb + 1 * 512), a1, 0, 0, 0);
#pragma unroll
  for (int kk = 0; kk < 16; kk += 2) {
    a0 = __builtin_amdgcn_mfma_f32_16x16x32_bf16(mk8(&raw[kk * 4]),
             *(const short8*)(Bb + (kk + 2) * 512), a0, 0, 0, 0);
    a1 = __builtin_amdgcn_mfma_f32_16x16x32_bf16(mk8(&raw[(kk + 1) * 4]),
             *(const short8*)(Bb + (kk + 3) * 512), a1, 0, 0, 0);
  }
  return a0 + a1;
}

// ---- prep: cast/reorder weights to bf16 in workspace --------------------
__global__ void prep_kernel(const float* __restrict__ Wz, const float* __restrict__ Wr,
                            const float* __restrict__ Wh, const float* __restrict__ W1,
                            const float* __restrict__ W2,
                            unsigned short* __restrict__ WgT,
                            unsigned short* __restrict__ W1T,
                            unsigned short* __restrict__ W2T) {
  const int total = 1536 * 576 + 512 * 512 + 64 * 512;
  for (int idx = blockIdx.x * 256 + threadIdx.x; idx < total; idx += gridDim.x * 256) {
    if (idx < 1536 * 576) {
      int row = idx / 576, k = idx % 576;
      float v;
      if (row < 512)       v = Wz[row * 576 + k];
      else if (row < 1024) v = Wr[(row - 512) * 576 + k];
      else {
        int r = row - 1024;
        v = (k < 64) ? Wh[r * 576 + 512 + k] : Wh[r * 576 + (k - 64)];
      }
      WgT[idx] = f2bf(v);
    } else if (idx < 1536 * 576 + 512 * 512) {
      int i = idx - 1536 * 576;
      W1T[i] = f2bf(W1[i]);
    } else {
      int i = idx - 1536 * 576 - 512 * 512;
      W2T[i] = f2bf(W2[i]);
    }
  }
}

// ---- recurrence: 32 WGs = 2 batch-groups x 16 column-slice WGs ----------
// Sync-free inner loop: tagged-word exchange, per-wave independent polls.
__global__ void __launch_bounds__(256, 1) recur_kernel(
    const float* __restrict__ x, const float* __restrict__ h0,
    const float* __restrict__ bz, const float* __restrict__ br,
    const float* __restrict__ bh, const unsigned short* __restrict__ WgT,
    u32* __restrict__ Hx, u32* __restrict__ RHx,
    unsigned short* __restrict__ h_all, float* __restrict__ h_last) {
  extern __shared__ char smem[];
  unsigned short* Wf = (unsigned short*)smem;   // 6 tiles x 18 kk x 64 lanes x 8 bf16

  const int wg = blockIdx.x;
  const int g = wg >> 4, w = wg & 15;
  const int tid = threadIdx.x;
  const int lane = tid & 63, wave = tid >> 6;
  const int crow = (lane >> 4) << 2;   // C/D row base
  const int ccol = lane & 15;          // C/D col == A row
  const int ko8 = (lane >> 4) << 3;    // k sub-offset (shorts / u32 words)

  // ---- one-time: weight fragments into LDS (read order == lane order) ----
  for (int i = tid; i < 6 * 18 * 64; i += 256) {
    int T = i / (18 * 64);
    int kk = (i >> 6) % 18;
    int l = i & 63;
    int row = (T >> 1) * 512 + w * 32 + (T & 1) * 16 + (l & 15);
    int k = kk * 32 + ((l >> 4) << 3);
    uint4 v = *(const uint4*)(WgT + (size_t)row * 576 + k);
    *(uint4*)(Wf + (size_t)i * 8) = v;
  }
  // ---- publish tagged h0 slice (tag 0) ----
  for (int i = tid; i < 512; i += 256) {
    int m = i >> 5, c = i & 31;
    float hv = h0[(size_t)(g * 16 + m) * 512 + w * 32 + c];
    st_u32(Hx + XIDX(0, g, m, w * 32 + c), (u32)f2bf(hv));
  }
  __syncthreads();   // Wf visibility within WG; cross-WG handled by polls

  const float* xrow = x + (size_t)(g * 16 + ccol) * (S_LEN * 64) + ko8;
  u64 raw[64];

  if (wave < 2) {
    // ================= zh-wave: z GEMM + h_hat GEMM + state update ==========
    const int colz = w * 32 + wave * 16 + ccol;
    const float bzv = bz[colz], bhv = bh[colz];
    const unsigned short* Bz = Wf + (size_t)wave * 18 * 512 + lane * 8;
    const unsigned short* Bh = Wf + (size_t)(4 + wave) * 18 * 512 + lane * 8;
    float hold[4];
#pragma unroll
    for (int j = 0; j < 4; ++j)
      hold[j] = h0[(size_t)(g * 16 + crow + j) * 512 + colz];

    float4 p0 = *(const float4*)(xrow);
    float4 p1 = *(const float4*)(xrow + 4);
    float4 p2 = *(const float4*)(xrow + 32);
    float4 p3 = *(const float4*)(xrow + 36);

    for (int t = 0; t < S_LEN; ++t) {
      const int pb = t & 1;
      const u64 pat = ((u64)(u32)t << 16) | ((u64)(u32)t << 48);
      short8 xa0, xa1;
      {
        union { u32 w4[4]; short8 v; } u;
        u.w4[0] = cvt2bf(p0.x, p0.y); u.w4[1] = cvt2bf(p0.z, p0.w);
        u.w4[2] = cvt2bf(p1.x, p1.y); u.w4[3] = cvt2bf(p1.z, p1.w);
        xa0 = u.v;
        u.w4[0] = cvt2bf(p2.x, p2.y); u.w4[1] = cvt2bf(p2.z, p2.w);
        u.w4[2] = cvt2bf(p3.x, p3.y); u.w4[3] = cvt2bf(p3.z, p3.w);
        xa1 = u.v;
      }
      // ---- poll h(t-1) ----
      const u64* hb = (const u64*)(Hx + XIDX(pb, g, ccol, ko8));
      unsigned it = 0;
      while (!__all(poll_tile(hb, pat, raw))) { if (++it > (1u << 22)) break; }
      f32x4 zacc = gemm18(Bz, xa0, xa1, raw);

      // prefetch x(t+1)
      const float* xn = xrow + (size_t)((t + 1 < S_LEN) ? t + 1 : t) * 64;
      p0 = *(const float4*)(xn);      p1 = *(const float4*)(xn + 4);
      p2 = *(const float4*)(xn + 32); p3 = *(const float4*)(xn + 36);

      float zv[4];
#pragma unroll
      for (int j = 0; j < 4; ++j)
        zv[j] = 1.f / (1.f + __expf(-(zacc[j] + bzv)));

      // ---- poll rh(t) ----
      const u64* rb = (const u64*)(RHx + XIDX(pb, g, ccol, ko8));
      it = 0;
      while (!__all(poll_tile(rb, pat, raw))) { if (++it > (1u << 22)) break; }
      f32x4 hacc = gemm18(Bh, xa0, xa1, raw);

#pragma unroll
      for (int j = 0; j < 4; ++j) {
        float e = __expf(2.f * (hacc[j] + bhv));
        float hh = 1.f - 2.f / (e + 1.f);
        float hn = (1.f - zv[j]) * hold[j] + zv[j] * hh;
        hold[j] = hn;
        unsigned short hbv = f2bf(hn);
        st_u32(Hx + XIDX(pb ^ 1, g, crow + j, colz), ((u32)(t + 1) << 16) | hbv);
        h_all[((size_t)(g * 16 + crow + j) * S_LEN + t) * 512 + colz] = hbv;
        if (t == S_LEN - 1) h_last[(size_t)(g * 16 + crow + j) * 512 + colz] = hn;
      }
    }
  } else {
    // ================= r-wave: r GEMM + publish rh ==========================
    const int nloc = (wave & 1) * 16 + ccol;
    const int colr = w * 32 + nloc;
    const float brv = br[colr];
    const unsigned short* Br = Wf + (size_t)wave * 18 * 512 + lane * 8;

    float4 p0 = *(const float4*)(xrow);
    float4 p1 = *(const float4*)(xrow + 4);
    float4 p2 = *(const float4*)(xrow + 32);
    float4 p3 = *(const float4*)(xrow + 36);

    for (int t = 0; t < S_LEN; ++t) {
      const int pb = t & 1;
      const u64 pat = ((u64)(u32)t << 16) | ((u64)(u32)t << 48);
      short8 xa0, xa1;
      {
        union { u32 w4[4]; short8 v; } u;
        u.w4[0] = cvt2bf(p0.x, p0.y); u.w4[1] = cvt2bf(p0.z, p0.w);
        u.w4[2] = cvt2bf(p1.x, p1.y); u.w4[3] = cvt2bf(p1.z, p1.w);
        xa0 = u.v;
        u.w4[0] = cvt2bf(p2.x, p2.y); u.w4[1] = cvt2bf(p2.z, p2.w);
        u.w4[2] = cvt2bf(p3.x, p3.y); u.w4[3] = cvt2bf(p3.z, p3.w);
        xa1 = u.v;
      }
      // ---- poll h(t-1) tile + the 4 own-column h words ----
      const u64* hb = (const u64*)(Hx + XIDX(pb, g, ccol, ko8));
      u32 hx[4];
      unsigned it = 0;
      for (;;) {
        bool ok = poll_tile(hb, pat, raw);
        u32 a32 = 0;
#pragma unroll
        for (int j = 0; j < 4; ++j) {
          hx[j] = ld_u32(Hx + XIDX(pb, g, crow + j, colr));
          a32 |= hx[j] ^ ((u32)t << 16);
        }
        ok = ok && ((a32 & 0xFFFF0000u) == 0);
        if (__all(ok)) break;
        if (++it > (1u << 22)) break;
      }
      f32x4 racc = gemm18(Br, xa0, xa1, raw);

      // prefetch x(t+1)
      const float* xn = xrow + (size_t)((t + 1 < S_LEN) ? t + 1 : t) * 64;
      p0 = *(const float4*)(xn);      p1 = *(const float4*)(xn + 4);
      p2 = *(const float4*)(xn + 32); p3 = *(const float4*)(xn + 36);

#pragma unroll
      for (int j = 0; j < 4; ++j) {
        float rv = 1.f / (1.f + __expf(-(racc[j] + brv)));
        float rh = rv * bf2f(hx[j] & 0xFFFFu);
        st_u32(RHx + XIDX(pb, g, crow + j, colr), ((u32)t << 16) | (u32)f2bf(rh));
      }
    }
  }
}

// ---- head: out = relu(h_all @ W1^T + b1) @ W2^T + b2 --------------------
__global__ void __launch_bounds__(256, 1) head_kernel(
    const unsigned short* __restrict__ h_all, const unsigned short* __restrict__ W1T,
    const unsigned short* __restrict__ W2T, const float* __restrict__ b1,
    const float* __restrict__ b2, float* __restrict__ out) {
  extern __shared__ char smem[];
  unsigned short* hs = (unsigned short*)smem;   // [64][520]
  unsigned short* act = hs + 64 * 520;          // [64][520]

  const int tid = threadIdx.x, lane = tid & 63, wave = tid >> 6;
  const int crow = (lane >> 4) << 2, ccol = lane & 15;
  const size_t row0 = (size_t)blockIdx.x * 64;

  for (int i = tid; i < 64 * 64; i += 256) {
    int r = i >> 6, c8 = i & 63;
    uint4 v = *(const uint4*)(h_all + (row0 + r) * 512 + c8 * 8);
    *(uint4*)(hs + r * 520 + c8 * 8) = v;
  }
  __syncthreads();

  f32x4 acc[8][4];
#pragma unroll
  for (int nt = 0; nt < 8; ++nt)
#pragma unroll
    for (int mt = 0; mt < 4; ++mt) acc[nt][mt] = {0.f, 0.f, 0.f, 0.f};

  for (int k = 0; k < 16; ++k) {
    short8 a[4];
#pragma unroll
    for (int mt = 0; mt < 4; ++mt)
      a[mt] = *(const short8*)(hs + (mt * 16 + ccol) * 520 + k * 32 + ((lane >> 4) << 3));
#pragma unroll
    for (int nt = 0; nt < 8; ++nt) {
      int n0 = (wave * 8 + nt) * 16;
      short8 b = *(const short8*)(W1T + (size_t)(n0 + ccol) * 512 + k * 32 + ((lane >> 4) << 3));
#pragma unroll
      for (int mt = 0; mt < 4; ++mt)
        acc[nt][mt] = __builtin_amdgcn_mfma_f32_16x16x32_bf16(a[mt], b, acc[nt][mt], 0, 0, 0);
    }
  }
#pragma unroll
  for (int nt = 0; nt < 8; ++nt) {
    int n = wave * 128 + nt * 16 + ccol;
    float bias = b1[n];
#pragma unroll
    for (int mt = 0; mt < 4; ++mt)
#pragma unroll
      for (int j = 0; j < 4; ++j) {
        float v = fmaxf(acc[nt][mt][j] + bias, 0.f);
        act[(mt * 16 + crow + j) * 520 + n] = f2bf(v);
      }
  }
  __syncthreads();
  for (int i = tid; i < 64 * 64; i += 256) {
    int r = i >> 6, c8 = i & 63;
    uint4 v = *(const uint4*)(W2T + (size_t)r * 512 + c8 * 8);
    *(uint4*)(hs + r * 520 + c8 * 8) = v;
  }
  __syncthreads();

  f32x4 acc2[4];
#pragma unroll
  for (int nt = 0; nt < 4; ++nt) acc2[nt] = {0.f, 0.f, 0.f, 0.f};
  for (int k = 0; k < 16; ++k) {
    short8 a = *(const short8*)(act + (wave * 16 + ccol) * 520 + k * 32 + ((lane >> 4) << 3));
#pragma unroll
    for (int nt = 0; nt < 4; ++nt) {
      short8 b = *(const short8*)(hs + (nt * 16 + ccol) * 520 + k * 32 + ((lane >> 4) << 3));
      acc2[nt] = __builtin_amdgcn_mfma_f32_16x16x32_bf16(a, b, acc2[nt], 0, 0, 0);
    }
  }
#pragma unroll
  for (int nt = 0; nt < 4; ++nt) {
    int o = nt * 16 + ccol;
    float bias = b2[o];
#pragma unroll
    for (int j = 0; j < 4; ++j) {
      int r = wave * 16 + crow + j;
      out[(row0 + r) * 64 + o] = acc2[nt][j] + bias;
    }
  }
}

extern "C" void kernel_launch(void* const* d_in, const int* in_sizes, int n_in,
                              void* d_out, int out_size, void* d_ws, size_t ws_size,
                              hipStream_t stream) {
  const float* x  = (const float*)d_in[0];
  const float* h0 = (const float*)d_in[1];
  const float* Wz = (const float*)d_in[2];
  const float* Wr = (const float*)d_in[3];
  const float* Wh = (const float*)d_in[4];
  const float* bz = (const float*)d_in[5];
  const float* br = (const float*)d_in[6];
  const float* bh = (const float*)d_in[7];
  const float* W1 = (const float*)d_in[8];
  const float* b1 = (const float*)d_in[9];
  const float* W2 = (const float*)d_in[10];
  const float* b2 = (const float*)d_in[11];

  char* ws = (char*)d_ws;
  size_t off = 0;
  u32* Hx  = (u32*)(ws + off); off += (size_t)2 * 2 * 16 * 512 * 4;   // 128 KB
  u32* RHx = (u32*)(ws + off); off += (size_t)2 * 2 * 16 * 512 * 4;   // 128 KB
  unsigned short* WgT   = (unsigned short*)(ws + off); off += (size_t)1536 * 576 * 2;
  unsigned short* W1T   = (unsigned short*)(ws + off); off += (size_t)512 * 512 * 2;
  unsigned short* W2T   = (unsigned short*)(ws + off); off += (size_t)64 * 512 * 2;
  unsigned short* h_all = (unsigned short*)(ws + off); off += (size_t)32 * 2048 * 512 * 2;

  float* out = (float*)d_out;
  float* h_last = out + (size_t)32 * 2048 * 64;

  hipLaunchKernelGGL(prep_kernel, dim3(1024), dim3(256), 0, stream,
                     Wz, Wr, Wh, W1, W2, WgT, W1T, W2T);

  const int recur_lds = 6 * 18 * 512 * 2;   // 110,592 B
  hipFuncSetAttribute(reinterpret_cast<const void*>(&recur_kernel),
                      hipFuncAttributeMaxDynamicSharedMemorySize, recur_lds);
  hipLaunchKernelGGL(recur_kernel, dim3(32), dim3(256), recur_lds, stream,
                     x, h0, bz, br, bh, WgT, Hx, RHx, h_all, h_last);

  const int head_lds = 2 * 64 * 520 * 2;
  hipFuncSetAttribute(reinterpret_cast<const void*>(&head_kernel),
                      hipFuncAttributeMaxDynamicSharedMemorySize, head_lds);
  hipLaunchKernelGGL(head_kernel, dim3(1024), dim3(256), head_lds, stream,
                     h_all, W1T, W2T, b1, b2, out);
}

// Round 4
// 16986.137 us; speedup vs baseline: 3.9925x; 3.9925x over previous
//
#include <hip/hip_runtime.h>
#include <stdint.h>

#define S_LEN 2048

typedef unsigned long long u64;
typedef unsigned int u32;
typedef __attribute__((ext_vector_type(8))) short short8;
typedef __attribute__((ext_vector_type(4))) float f32x4;

// u32 index into Hx/RHx: [buf 2][grp 2][m 16][col 512], word = (tag16<<16)|bf16
#define XIDX(pbuf, grp, m, c) (((((pbuf)*2 + (grp))*16 + (m))*512) + (c))

__device__ __forceinline__ unsigned short f2bf(float f) {
  union { float f; u32 u; } v; v.f = f;
  u32 u = v.u;
  u = (u + 0x7FFFu + ((u >> 16) & 1u)) >> 16;   // round-to-nearest-even
  return (unsigned short)u;
}
__device__ __forceinline__ float bf2f(u32 lo16) {
  union { u32 u; float f; } v; v.u = lo16 << 16; return v.f;
}
__device__ __forceinline__ u32 cvt2bf(float lo, float hi) {
  u32 r; asm("v_cvt_pk_bf16_f32 %0, %1, %2" : "=v"(r) : "v"(lo), "v"(hi)); return r;
}
__device__ __forceinline__ void st_u32(u32* p, u32 v) {
  __hip_atomic_store(p, v, __ATOMIC_RELAXED, __HIP_MEMORY_SCOPE_AGENT);
}
__device__ __forceinline__ u32 ld_u32(const u32* p) {
  return __hip_atomic_load(p, __ATOMIC_RELAXED, __HIP_MEMORY_SCOPE_AGENT);
}
__device__ __forceinline__ u64 ld_u64a(const u64* p) {
  return __hip_atomic_load(p, __ATOMIC_RELAXED, __HIP_MEMORY_SCOPE_AGENT);
}
__device__ __forceinline__ u32 detag(u64 q) {
  return (u32)(q & 0xFFFFu) | (u32)((q >> 16) & 0xFFFF0000u);
}

// Spin on 16 sentinel words (row 0, col 32*w') until all carry `tag`.
__device__ __forceinline__ void probe16(const u32* Xgrp, u32 tag, int lane) {
  const u32* p = Xgrp + (lane & 15) * 32;
  unsigned it = 0;
  for (;;) {
    u32 v = ld_u32(p);
    if (__all((int)((v >> 16) == tag))) break;
    if (++it > (1u << 22)) break;     // safety: never hang the harness
  }
}

// Bulk-load this wave's quarter (chunks kq*4..kq*4+3), verify tags, retry,
// detag and write fragment-layout LDS. 16 u64 = 32 VGPRs live.
__device__ __forceinline__ void stage_quarter(const u32* Xgrp, u64 pat, int kq, int lane,
                                              unsigned short* Adst) {
  const u64* base = (const u64*)(Xgrp + (lane & 15) * 512 + kq * 128 + ((lane >> 4) << 3));
  u64 r[16];
  for (unsigned it = 0;; ++it) {
    u64 acc = 0;
#pragma unroll
    for (int c = 0; c < 4; ++c)
#pragma unroll
      for (int q = 0; q < 4; ++q) {
        u64 v = ld_u64a(base + c * 16 + q);
        r[c * 4 + q] = v;
        acc |= v ^ pat;
      }
    if (__all((int)((acc & 0xFFFF0000FFFF0000ULL) == 0))) break;
    if (it > (1u << 20)) break;       // safety
  }
#pragma unroll
  for (int c = 0; c < 4; ++c) {
    uint4 pk;
    pk.x = detag(r[c * 4 + 0]); pk.y = detag(r[c * 4 + 1]);
    pk.z = detag(r[c * 4 + 2]); pk.w = detag(r[c * 4 + 3]);
    *(uint4*)(Adst + (size_t)((kq * 4 + c) * 64 + lane) * 8) = pk;
  }
}

__device__ __forceinline__ f32x4 gemm_lds(const unsigned short* Bb, const unsigned short* A,
                                          int lane, short8 xa0, short8 xa1) {
  f32x4 a0 = {0.f, 0.f, 0.f, 0.f}, a1 = {0.f, 0.f, 0.f, 0.f};
  a0 = __builtin_amdgcn_mfma_f32_16x16x32_bf16(xa0, *(const short8*)(Bb + 0 * 512), a0, 0, 0, 0);
  a1 = __builtin_amdgcn_mfma_f32_16x16x32_bf16(xa1, *(const short8*)(Bb + 1 * 512), a1, 0, 0, 0);
#pragma unroll
  for (int kk = 0; kk < 16; kk += 2) {
    short8 u = *(const short8*)(A + (size_t)(kk * 64 + lane) * 8);
    short8 v = *(const short8*)(A + (size_t)((kk + 1) * 64 + lane) * 8);
    a0 = __builtin_amdgcn_mfma_f32_16x16x32_bf16(u, *(const short8*)(Bb + (kk + 2) * 512), a0, 0, 0, 0);
    a1 = __builtin_amdgcn_mfma_f32_16x16x32_bf16(v, *(const short8*)(Bb + (kk + 3) * 512), a1, 0, 0, 0);
  }
  return a0 + a1;
}

// ---- prep: cast/reorder weights to bf16 in workspace --------------------
__global__ void prep_kernel(const float* __restrict__ Wz, const float* __restrict__ Wr,
                            const float* __restrict__ Wh, const float* __restrict__ W1,
                            const float* __restrict__ W2,
                            unsigned short* __restrict__ WgT,
                            unsigned short* __restrict__ W1T,
                            unsigned short* __restrict__ W2T) {
  const int total = 1536 * 576 + 512 * 512 + 64 * 512;
  for (int idx = blockIdx.x * 256 + threadIdx.x; idx < total; idx += gridDim.x * 256) {
    if (idx < 1536 * 576) {
      int row = idx / 576, k = idx % 576;
      float v;
      if (row < 512)       v = Wz[row * 576 + k];
      else if (row < 1024) v = Wr[(row - 512) * 576 + k];
      else {
        int r = row - 1024;
        v = (k < 64) ? Wh[r * 576 + 512 + k] : Wh[r * 576 + (k - 64)];
      }
      WgT[idx] = f2bf(v);
    } else if (idx < 1536 * 576 + 512 * 512) {
      int i = idx - 1536 * 576;
      W1T[i] = f2bf(W1[i]);
    } else {
      int i = idx - 1536 * 576 - 512 * 512;
      W2T[i] = f2bf(W2[i]);
    }
  }
}

// ---- recurrence: 32 WGs = 2 batch-groups x 16 column-slice WGs ----------
// Tagged-word exchange; 4 waves cooperatively stage tile quarters into LDS.
__global__ void __launch_bounds__(256, 1) recur_kernel(
    const float* __restrict__ x, const float* __restrict__ h0,
    const float* __restrict__ bz, const float* __restrict__ br,
    const float* __restrict__ bh, const unsigned short* __restrict__ WgT,
    u32* __restrict__ Hx, u32* __restrict__ RHx,
    unsigned short* __restrict__ h_all, float* __restrict__ h_last) {
  extern __shared__ char smem[];
  unsigned short* Wf  = (unsigned short*)smem;     // 6 tiles x 18 kk x 64 x 8 bf16
  unsigned short* Ah  = Wf + 6 * 18 * 64 * 8;      // 16 kk x 64 x 8 bf16
  unsigned short* Arh = Ah + 16 * 64 * 8;          // 16 kk x 64 x 8 bf16

  const int wg = blockIdx.x;
  const int g = wg >> 4, w = wg & 15;
  const int tid = threadIdx.x;
  const int lane = tid & 63, wave = tid >> 6;
  const int crow = (lane >> 4) << 2;   // C/D row base
  const int ccol = lane & 15;          // C/D col == A row
  const int ko8 = (lane >> 4) << 3;    // k sub-offset

  // ---- one-time: weight fragments into LDS (read order == lane order) ----
  for (int i = tid; i < 6 * 18 * 64; i += 256) {
    int T = i / (18 * 64);
    int kk = (i >> 6) % 18;
    int l = i & 63;
    int row = (T >> 1) * 512 + w * 32 + (T & 1) * 16 + (l & 15);
    int k = kk * 32 + ((l >> 4) << 3);
    uint4 v = *(const uint4*)(WgT + (size_t)row * 576 + k);
    *(uint4*)(Wf + (size_t)i * 8) = v;
  }
  // ---- publish tagged h0 slice (tag 0, buffer 0) ----
  for (int i = tid; i < 512; i += 256) {
    int m = i >> 5, c = i & 31;
    float hv = h0[(size_t)(g * 16 + m) * 512 + w * 32 + c];
    st_u32(Hx + XIDX(0, g, m, w * 32 + c), (u32)f2bf(hv));
  }
  __syncthreads();

  const float* xrow = x + (size_t)(g * 16 + ccol) * (S_LEN * 64) + ko8;
  const bool is_zh = (wave < 2);
  const int nloc = (wave & 1) * 16 + ccol;          // own output col within slice
  const int colg = w * 32 + nloc;                   // global col
  const float bzv = is_zh ? bz[colg] : 0.f;
  const float bhv = is_zh ? bh[colg] : 0.f;
  const float brv = is_zh ? 0.f : br[colg];
  const unsigned short* Bza = Wf + (size_t)wave * 18 * 512 + lane * 8;  // z or r tile
  const unsigned short* Bh  = Wf + (size_t)(4 + (wave & 1)) * 18 * 512 + lane * 8;

  float hold[4];
  if (is_zh) {
#pragma unroll
    for (int j = 0; j < 4; ++j)
      hold[j] = h0[(size_t)(g * 16 + crow + j) * 512 + colg];
  }

  float4 p0 = *(const float4*)(xrow);
  float4 p1 = *(const float4*)(xrow + 4);
  float4 p2 = *(const float4*)(xrow + 32);
  float4 p3 = *(const float4*)(xrow + 36);

  for (int t = 0; t < S_LEN; ++t) {
    const int pb = t & 1;
    const u32 tag = (u32)t;
    const u64 pat = ((u64)tag << 16) | ((u64)tag << 48);
    u32* Hgrp  = Hx  + XIDX(pb, g, 0, 0);
    u32* RHgrp = RHx + XIDX(pb, g, 0, 0);

    short8 xa0, xa1;
    {
      union { u32 w4[4]; short8 v; } u;
      u.w4[0] = cvt2bf(p0.x, p0.y); u.w4[1] = cvt2bf(p0.z, p0.w);
      u.w4[2] = cvt2bf(p1.x, p1.y); u.w4[3] = cvt2bf(p1.z, p1.w);
      xa0 = u.v;
      u.w4[0] = cvt2bf(p2.x, p2.y); u.w4[1] = cvt2bf(p2.z, p2.w);
      u.w4[2] = cvt2bf(p3.x, p3.y); u.w4[3] = cvt2bf(p3.z, p3.w);
      xa1 = u.v;
    }

    // ===== phase A: stage h(t-1) quarters -> Ah =====
    probe16(Hgrp, tag, lane);
    stage_quarter(Hgrp, pat, wave, lane, Ah);
    __syncthreads();   // S1

    float zv[4];
    if (is_zh) {
      f32x4 zacc = gemm_lds(Bza, Ah, lane, xa0, xa1);
#pragma unroll
      for (int j = 0; j < 4; ++j)
        zv[j] = 1.f / (1.f + __expf(-(zacc[j] + bzv)));
    } else {
      f32x4 racc = gemm_lds(Bza, Ah, lane, xa0, xa1);
#pragma unroll
      for (int j = 0; j < 4; ++j) {
        // h[crow+j][colg] from Ah fragment layout (chunk w, sub nloc)
        u32 hbf = Ah[(size_t)((w * 4 + (nloc >> 3)) * 16 + 0) * 0 +
                     (size_t)((w) * 64 + ((nloc >> 3) << 4) + (crow + j)) * 8 + (nloc & 7)];
        float rv = 1.f / (1.f + __expf(-(racc[j] + brv)));
        float rh = rv * bf2f(hbf);
        st_u32(RHx + XIDX(pb, g, crow + j, colg), (tag << 16) | (u32)f2bf(rh));
      }
    }

    // prefetch x(t+1)
    {
      const float* xn = xrow + (size_t)((t + 1 < S_LEN) ? t + 1 : t) * 64;
      p0 = *(const float4*)(xn);      p1 = *(const float4*)(xn + 4);
      p2 = *(const float4*)(xn + 32); p3 = *(const float4*)(xn + 36);
    }

    // ===== phase B: stage rh(t) quarters -> Arh =====
    probe16(RHgrp, tag, lane);
    stage_quarter(RHgrp, pat, wave, lane, Arh);
    __syncthreads();   // S2

    if (is_zh) {
      f32x4 hacc = gemm_lds(Bh, Arh, lane, xa0, xa1);
#pragma unroll
      for (int j = 0; j < 4; ++j) {
        float e = __expf(2.f * (hacc[j] + bhv));
        float hh = 1.f - 2.f / (e + 1.f);
        float hn = (1.f - zv[j]) * hold[j] + zv[j] * hh;
        hold[j] = hn;
        unsigned short hbv = f2bf(hn);
        st_u32(Hx + XIDX(pb ^ 1, g, crow + j, colg), ((u32)(t + 1) << 16) | hbv);
        h_all[((size_t)(g * 16 + crow + j) * S_LEN + t) * 512 + colg] = hbv;
        if (t == S_LEN - 1) h_last[(size_t)(g * 16 + crow + j) * 512 + colg] = hn;
      }
    }
  }
}

// ---- head: out = relu(h_all @ W1^T + b1) @ W2^T + b2 --------------------
__global__ void __launch_bounds__(256, 1) head_kernel(
    const unsigned short* __restrict__ h_all, const unsigned short* __restrict__ W1T,
    const unsigned short* __restrict__ W2T, const float* __restrict__ b1,
    const float* __restrict__ b2, float* __restrict__ out) {
  extern __shared__ char smem[];
  unsigned short* hs = (unsigned short*)smem;   // [64][520]
  unsigned short* act = hs + 64 * 520;          // [64][520]

  const int tid = threadIdx.x, lane = tid & 63, wave = tid >> 6;
  const int crow = (lane >> 4) << 2, ccol = lane & 15;
  const size_t row0 = (size_t)blockIdx.x * 64;

  for (int i = tid; i < 64 * 64; i += 256) {
    int r = i >> 6, c8 = i & 63;
    uint4 v = *(const uint4*)(h_all + (row0 + r) * 512 + c8 * 8);
    *(uint4*)(hs + r * 520 + c8 * 8) = v;
  }
  __syncthreads();

  f32x4 acc[8][4];
#pragma unroll
  for (int nt = 0; nt < 8; ++nt)
#pragma unroll
    for (int mt = 0; mt < 4; ++mt) acc[nt][mt] = {0.f, 0.f, 0.f, 0.f};

  for (int k = 0; k < 16; ++k) {
    short8 a[4];
#pragma unroll
    for (int mt = 0; mt < 4; ++mt)
      a[mt] = *(const short8*)(hs + (mt * 16 + ccol) * 520 + k * 32 + ((lane >> 4) << 3));
#pragma unroll
    for (int nt = 0; nt < 8; ++nt) {
      int n0 = (wave * 8 + nt) * 16;
      short8 b = *(const short8*)(W1T + (size_t)(n0 + ccol) * 512 + k * 32 + ((lane >> 4) << 3));
#pragma unroll
      for (int mt = 0; mt < 4; ++mt)
        acc[nt][mt] = __builtin_amdgcn_mfma_f32_16x16x32_bf16(a[mt], b, acc[nt][mt], 0, 0, 0);
    }
  }
#pragma unroll
  for (int nt = 0; nt < 8; ++nt) {
    int n = wave * 128 + nt * 16 + ccol;
    float bias = b1[n];
#pragma unroll
    for (int mt = 0; mt < 4; ++mt)
#pragma unroll
      for (int j = 0; j < 4; ++j) {
        float v = fmaxf(acc[nt][mt][j] + bias, 0.f);
        act[(mt * 16 + crow + j) * 520 + n] = f2bf(v);
      }
  }
  __syncthreads();
  for (int i = tid; i < 64 * 64; i += 256) {
    int r = i >> 6, c8 = i & 63;
    uint4 v = *(const uint4*)(W2T + (size_t)r * 512 + c8 * 8);
    *(uint4*)(hs + r * 520 + c8 * 8) = v;
  }
  __syncthreads();

  f32x4 acc2[4];
#pragma unroll
  for (int nt = 0; nt < 4; ++nt) acc2[nt] = {0.f, 0.f, 0.f, 0.f};
  for (int k = 0; k < 16; ++k) {
    short8 a = *(const short8*)(act + (wave * 16 + ccol) * 520 + k * 32 + ((lane >> 4) << 3));
#pragma unroll
    for (int nt = 0; nt < 4; ++nt) {
      short8 b = *(const short8*)(hs + (nt * 16 + ccol) * 520 + k * 32 + ((lane >> 4) << 3));
      acc2[nt] = __builtin_amdgcn_mfma_f32_16x16x32_bf16(a, b, acc2[nt], 0, 0, 0);
    }
  }
#pragma unroll
  for (int nt = 0; nt < 4; ++nt) {
    int o = nt * 16 + ccol;
    float bias = b2[o];
#pragma unroll
    for (int j = 0; j < 4; ++j) {
      int r = wave * 16 + crow + j;
      out[(row0 + r) * 64 + o] = acc2[nt][j] + bias;
    }
  }
}

extern "C" void kernel_launch(void* const* d_in, const int* in_sizes, int n_in,
                              void* d_out, int out_size, void* d_ws, size_t ws_size,
                              hipStream_t stream) {
  const float* x  = (const float*)d_in[0];
  const float* h0 = (const float*)d_in[1];
  const float* Wz = (const float*)d_in[2];
  const float* Wr = (const float*)d_in[3];
  const float* Wh = (const float*)d_in[4];
  const float* bz = (const float*)d_in[5];
  const float* br = (const float*)d_in[6];
  const float* bh = (const float*)d_in[7];
  const float* W1 = (const float*)d_in[8];
  const float* b1 = (const float*)d_in[9];
  const float* W2 = (const float*)d_in[10];
  const float* b2 = (const float*)d_in[11];

  char* ws = (char*)d_ws;
  size_t off = 0;
  u32* Hx  = (u32*)(ws + off); off += (size_t)2 * 2 * 16 * 512 * 4;   // 128 KB
  u32* RHx = (u32*)(ws + off); off += (size_t)2 * 2 * 16 * 512 * 4;   // 128 KB
  unsigned short* WgT   = (unsigned short*)(ws + off); off += (size_t)1536 * 576 * 2;
  unsigned short* W1T   = (unsigned short*)(ws + off); off += (size_t)512 * 512 * 2;
  unsigned short* W2T   = (unsigned short*)(ws + off); off += (size_t)64 * 512 * 2;
  unsigned short* h_all = (unsigned short*)(ws + off); off += (size_t)32 * 2048 * 512 * 2;

  float* out = (float*)d_out;
  float* h_last = out + (size_t)32 * 2048 * 64;

  hipLaunchKernelGGL(prep_kernel, dim3(1024), dim3(256), 0, stream,
                     Wz, Wr, Wh, W1, W2, WgT, W1T, W2T);

  const int recur_lds = (6 * 18 * 64 * 8 + 2 * 16 * 64 * 8) * 2;   // 143,360 B
  hipFuncSetAttribute(reinterpret_cast<const void*>(&recur_kernel),
                      hipFuncAttributeMaxDynamicSharedMemorySize, recur_lds);
  hipLaunchKernelGGL(recur_kernel, dim3(32), dim3(256), recur_lds, stream,
                     x, h0, bz, br, bh, WgT, Hx, RHx, h_all, h_last);

  const int head_lds = 2 * 64 * 520 * 2;
  hipFuncSetAttribute(reinterpret_cast<const void*>(&head_kernel),
                      hipFuncAttributeMaxDynamicSharedMemorySize, head_lds);
  hipLaunchKernelGGL(head_kernel, dim3(1024), dim3(256), head_lds, stream,
                     h_all, W1T, W2T, b1, b2, out);
}